// Round 1
// baseline (636.657 us; speedup 1.0000x reference)
//
#include <hip/hip_runtime.h>
#include <math.h>

#define NROWS 65536
#define DIM 256
#define KC 1024

// ---------------------------------------------------------------------------
// Kernel 1: row norms for inputs (xn) and embeddings (en); zero loss accum.
// One 64-lane wave per row; float4 loads; deterministic shuffle-tree sum
// (error profile ~ numpy pairwise, important: xn feeds the argmin scores).
// ---------------------------------------------------------------------------
__global__ void __launch_bounds__(256) vq_norms(const float* __restrict__ x,
                                                const float* __restrict__ e,
                                                float* __restrict__ xn,
                                                float* __restrict__ en,
                                                float* __restrict__ accum) {
    if (blockIdx.x == 0 && threadIdx.x == 0) *accum = 0.0f;
    const int wave = threadIdx.x >> 6;
    const int lane = threadIdx.x & 63;
    const int row = blockIdx.x * 4 + wave;   // grid sized exactly (NROWS+KC)/4
    const float* src;
    float* dst;
    if (row < NROWS) {
        src = x + (size_t)row * DIM;
        dst = xn + row;
    } else {
        int er = row - NROWS;                // always < KC by grid sizing
        src = e + (size_t)er * DIM;
        dst = en + er;
    }
    float4 v = ((const float4*)src)[lane];
    float s = (v.x * v.x + v.y * v.y) + (v.z * v.z + v.w * v.w);
#pragma unroll
    for (int off = 1; off < 64; off <<= 1)
        s += __shfl_xor(s, off, 64);
    if (lane == 0) *dst = s;
}

// ---------------------------------------------------------------------------
// Kernel 2: fused distance-GEMM + row argmin.
// Block = 256 threads, tile = 128 rows x 128 codes, BK=32.
// Per thread: 8x8 microtile (rows ty+i*16, codes tx+j*16).
// score = fmaf(-2, dot, xn+en)  -- bit-matches np's (xn+en) - 2*dot.
// Ties -> smallest index (np argmin first-occurrence semantics).
// ---------------------------------------------------------------------------
__global__ void __launch_bounds__(256) vq_argmin(const float* __restrict__ X,
                                                 const float* __restrict__ E,
                                                 const float* __restrict__ xn,
                                                 const float* __restrict__ en,
                                                 int* __restrict__ oidx) {
    __shared__ float Xs[32][129];   // +1 pad: transpose-store bank spread
    __shared__ float Es[32][129];
    __shared__ float rv[128][17];
    __shared__ int   ri[128][17];

    const int tid = threadIdx.x;
    const int tx = tid & 15;
    const int ty = tid >> 4;
    const size_t rowBase = (size_t)blockIdx.x * 128;

    const int lr = tid >> 3;         // load row-in-tile 0..31
    const int lc = (tid & 7) * 4;    // load col (float4 granule)

    float bestV[8];
    int bestI[8];
#pragma unroll
    for (int i = 0; i < 8; i++) { bestV[i] = INFINITY; bestI[i] = 0; }

    float xnr[8];
#pragma unroll
    for (int i = 0; i < 8; i++) xnr[i] = xn[rowBase + ty + i * 16];

    for (int cc = 0; cc < KC; cc += 128) {
        float dot[8][8];
#pragma unroll
        for (int i = 0; i < 8; i++)
#pragma unroll
            for (int j = 0; j < 8; j++) dot[i][j] = 0.0f;

        for (int dk = 0; dk < DIM; dk += 32) {
            __syncthreads();
#pragma unroll
            for (int g = 0; g < 4; g++) {
                int r = lr + g * 32;
                float4 vx = *(const float4*)(X + (rowBase + r) * DIM + dk + lc);
                Xs[lc + 0][r] = vx.x;
                Xs[lc + 1][r] = vx.y;
                Xs[lc + 2][r] = vx.z;
                Xs[lc + 3][r] = vx.w;
                float4 ve = *(const float4*)(E + (size_t)(cc + r) * DIM + dk + lc);
                Es[lc + 0][r] = ve.x;
                Es[lc + 1][r] = ve.y;
                Es[lc + 2][r] = ve.z;
                Es[lc + 3][r] = ve.w;
            }
            __syncthreads();
#pragma unroll
            for (int d = 0; d < 32; d++) {
                float a[8], b[8];
#pragma unroll
                for (int i = 0; i < 8; i++) a[i] = Xs[d][ty + i * 16];
#pragma unroll
                for (int j = 0; j < 8; j++) b[j] = Es[d][tx + j * 16];
#pragma unroll
                for (int i = 0; i < 8; i++)
#pragma unroll
                    for (int j = 0; j < 8; j++)
                        dot[i][j] = fmaf(a[i], b[j], dot[i][j]);
            }
        }
#pragma unroll
        for (int j = 0; j < 8; j++) {
            int code = cc + tx + j * 16;
            float enc = en[code];
#pragma unroll
            for (int i = 0; i < 8; i++) {
                float s = fmaf(-2.0f, dot[i][j], xnr[i] + enc);
                if (s < bestV[i] || (s == bestV[i] && code < bestI[i])) {
                    bestV[i] = s;
                    bestI[i] = code;
                }
            }
        }
    }

    // cross-thread (over tx) argmin reduction per row
#pragma unroll
    for (int i = 0; i < 8; i++) {
        rv[ty + i * 16][tx] = bestV[i];
        ri[ty + i * 16][tx] = bestI[i];
    }
    __syncthreads();
    if (tid < 128) {
        float bv = rv[tid][0];
        int bi = ri[tid][0];
#pragma unroll
        for (int t = 1; t < 16; t++) {
            float v = rv[tid][t];
            int ix = ri[tid][t];
            if (v < bv || (v == bv && ix < bi)) { bv = v; bi = ix; }
        }
        oidx[rowBase + tid] = bi;
    }
}

// ---------------------------------------------------------------------------
// Kernel 3: gather quantized rows + fused squared-diff partial sums.
// 256 threads = one thread per dim element; 16 rows per block.
// ---------------------------------------------------------------------------
__global__ void __launch_bounds__(256) vq_gather(const float* __restrict__ X,
                                                 const float* __restrict__ E,
                                                 const int* __restrict__ idxs,
                                                 float* __restrict__ out,
                                                 float* __restrict__ accum) {
    const int tid = threadIdx.x;
    const size_t rowBase = (size_t)blockIdx.x * 16;
    float part = 0.0f;
#pragma unroll
    for (int r = 0; r < 16; r++) {
        size_t row = rowBase + r;
        int code = idxs[row];
        float q = E[(size_t)code * DIM + tid];
        float xv = X[row * DIM + tid];
        out[row * DIM + tid] = q;
        float d = q - xv;
        part = fmaf(d, d, part);
    }
#pragma unroll
    for (int off = 1; off < 64; off <<= 1)
        part += __shfl_xor(part, off, 64);
    __shared__ float red[4];
    if ((tid & 63) == 0) red[tid >> 6] = part;
    __syncthreads();
    if (tid == 0) {
        float s = (red[0] + red[1]) + (red[2] + red[3]);
        atomicAdd(accum, s);
    }
}

// ---------------------------------------------------------------------------
// Kernel 4: finalize scalar loss. mean = sum / 2^24 (exact divide),
// vq_loss = q_latent + e_latent = 2*mean (exact add).
// ---------------------------------------------------------------------------
__global__ void vq_finalize(const float* __restrict__ accum,
                            float* __restrict__ loss) {
    float m = *accum * (1.0f / 16777216.0f);
    *loss = m + m;
}

extern "C" void kernel_launch(void* const* d_in, const int* in_sizes, int n_in,
                              void* d_out, int out_size, void* d_ws, size_t ws_size,
                              hipStream_t stream) {
    const float* X = (const float*)d_in[0];   // [65536, 256]
    const float* E = (const float*)d_in[1];   // [1024, 256]
    float* out = (float*)d_out;               // [65536*256] quantized + [1] loss

    char* ws = (char*)d_ws;
    float* xn    = (float*)ws;                              // 65536 f32
    float* en    = (float*)(ws + 262144);                   // 1024 f32
    int*   idxs  = (int*)  (ws + 262144 + 4096);            // 65536 i32
    float* accum = (float*)(ws + 262144 + 4096 + 262144);   // 1 f32

    vq_norms  <<<(NROWS + KC) / 4, 256, 0, stream>>>(X, E, xn, en, accum);
    vq_argmin <<<NROWS / 128,      256, 0, stream>>>(X, E, xn, en, idxs);
    vq_gather <<<NROWS / 16,       256, 0, stream>>>(X, E, idxs, out, accum);
    vq_finalize<<<1, 1, 0, stream>>>(accum, out + (size_t)NROWS * DIM);
}